// Round 4
// baseline (319.357 us; speedup 1.0000x reference)
//
#include <hip/hip_runtime.h>

// BERTEmbedding: out[p, 0:256]   = x[p,0:10] @ W^T + b       (fp32)
//                out[p, 256:512] = sinusoidal PE row doy[p]  (fp32)
// p over B*S = 131072 positions. ALL fp32 (inputs per reference; output is
// the reference's fp32 return). Established empirically:
//  - r1: reading fp32 inputs as bf16 pairs -> NaN (mantissa bits as exponent)
//  - r3: runtime dtype ballot -> flags=0 (fp32/int32), output identical to r2
//  - r2/r3 absmax 9.33 = bf16-pair-written-into-fp32-buffer signature
//    (plausible magnitudes from bf16 high bits; half the buffer unwritten)
//
// Layout: 1 wave per position; lane j handles dims [4j,4j+4) of both halves.
// Block = 256 threads = 4 positions; each position writes a contiguous 2 KB
// row (full cache lines). Write-BW-bound: ~268 MB out -> ~43 us floor.

__global__ __launch_bounds__(256) void bert_embed_kernel(
    const float* __restrict__ x,      // [BS, 10]  fp32
    const int*   __restrict__ doy,    // [BS]      int32
    const float* __restrict__ W,      // [256, 10] fp32
    const float* __restrict__ bvec,   // [256]     fp32
    float*       __restrict__ out,    // [BS, 512] fp32
    int BS)
{
    const int lane = threadIdx.x & 63;
    const int wave = threadIdx.x >> 6;
    const int p = blockIdx.x * 4 + wave;
    if (p >= BS) return;

    // --- x[p, 0:10]: wave-uniform row, 40 B, 8-B aligned ---
    const float2* xp = (const float2*)(x + (size_t)p * 10);
    float xf[10];
    #pragma unroll
    for (int c = 0; c < 5; ++c) {
        float2 v = xp[c];
        xf[2 * c]     = v.x;
        xf[2 * c + 1] = v.y;
    }

    const int d0 = lane * 4;

    // --- bias b[d0..d0+3]: one float4 (16-B aligned) ---
    float4 bv = *(const float4*)(bvec + d0);
    float acc[4] = {bv.x, bv.y, bv.z, bv.w};

    // --- W rows d0..d0+3: 40 floats = 160 B/lane, 16-B aligned, L1-resident ---
    {
        const float4* wp = (const float4*)(W + (size_t)d0 * 10);
        float wf[40];
        #pragma unroll
        for (int c = 0; c < 10; ++c) {
            float4 v = wp[c];
            wf[4 * c + 0] = v.x; wf[4 * c + 1] = v.y;
            wf[4 * c + 2] = v.z; wf[4 * c + 3] = v.w;
        }
        #pragma unroll
        for (int r = 0; r < 4; ++r) {
            #pragma unroll
            for (int f = 0; f < 10; ++f)
                acc[r] = fmaf(xf[f], wf[10 * r + f], acc[r]);
        }
    }

    // --- PE dims 4*lane..4*lane+3: pairs j = 2*lane, 2*lane+1 ---
    // pe[pos, 2j]   = sin(pos * 10000^(-j/128))
    // pe[pos, 2j+1] = cos(same angle)
    // rev = angle/(2*pi) = pos * 2^(-j*log2(1e4)/128 - log2(2*pi))
    const float pos = (float)doy[p];
    float pe[4];
    #pragma unroll
    for (int q = 0; q < 2; ++q) {
        float j = (float)(2 * lane + q);
        float e = __builtin_amdgcn_exp2f(
            fmaf(j, -0.10381025296522976f, -2.651496129472319f));
        float rev = pos * e;
        float fr = rev - floorf(rev);              // [0,1) revolutions
        pe[2 * q]     = __builtin_amdgcn_sinf(fr); // sin(2*pi*fr)
        pe[2 * q + 1] = __builtin_amdgcn_cosf(fr); // cos(2*pi*fr)
    }

    // --- stores: two float4 (16 B) per lane; contiguous 2 KB row/position ---
    float* o = out + (size_t)p * 512;
    float4 s0 = {acc[0], acc[1], acc[2], acc[3]};
    float4 s1 = {pe[0],  pe[1],  pe[2],  pe[3]};
    *(float4*)(o + d0)       = s0;
    *(float4*)(o + 256 + d0) = s1;
}

extern "C" void kernel_launch(void* const* d_in, const int* in_sizes, int n_in,
                              void* d_out, int out_size, void* d_ws, size_t ws_size,
                              hipStream_t stream) {
    const float* x    = (const float*)d_in[0];
    const int*   doy  = (const int*)d_in[1];
    const float* W    = (const float*)d_in[2];
    const float* bvec = (const float*)d_in[3];
    float*       out  = (float*)d_out;

    const int BS = in_sizes[1];           // B*S = 131072 positions
    const int blocks = (BS + 3) / 4;      // 4 positions per 256-thread block
    bert_embed_kernel<<<blocks, 256, 0, stream>>>(x, doy, W, bvec, out, BS);
}